// Round 9
// baseline (143.958 us; speedup 1.0000x reference)
//
#include <hip/hip_runtime.h>

#define BB 2
#define NN 16384
#define CC 64
#define SS 4096
#define KK 32
#define R2 0.16f   // RADIUS^2

// spatial grid: cell = RADIUS, 24^3 cells covering [-4.8, 4.8] (clamped; the
// clamp is monotone so the 3x3x3 neighborhood remains a superset of the ball
// for ANY input magnitude — tail points just pile into edge cells)
#define GD   24
#define GC   (GD * GD * GD)       // 13824 cells per batch
#define CAPC 112                  // per-cell bucket capacity (center cell ~66)
#define CAP  512                  // per-wave hit-list capacity (max expected ~360)
#define CAPL (CAP / 64)           // 8 register chunks for selection

typedef __bf16 bf16x8 __attribute__((ext_vector_type(8)));
typedef float  f32x4  __attribute__((ext_vector_type(4)));

#define MFMA(a, b, c) __builtin_amdgcn_mfma_f32_16x16x32_bf16((a), (b), (c), 0, 0, 0)

static __device__ __forceinline__ ushort f2bf(float f) {
    __bf16 h = (__bf16)f;
    return *(ushort*)&h;
}

static __device__ __forceinline__ int cellc(float x) {
    int i = (int)floorf(x * 2.5f + 12.0f);
    return i < 0 ? 0 : (i > GD - 1 ? GD - 1 : i);
}

// workspace section offsets (bytes), all 16B aligned
#define WS_PTS4   0          // pts4:    2*16384*16    =   524,288
#define WS_FEAT   524288     // feat_nc: 2*16384*64*2  = 4,194,304
#define WS_W1T    4718592    // 64*96*2   = 12,288
#define WS_W2T    4730880    // 64*64*2   =  8,192
#define WS_W3T    4739072    // 128*64*2  = 16,384
#define WS_CNT    4755456    // counts: 2*13824*4 = 110,592
#define WS_LPTS   4866048    // coord+id buckets: 2*13824*112*16 = 49,545,216
                             // (end 54,411,264; id packed in .w — no list[])

// prep index ranges (block-granular: T_SIDX = 328 blocks exactly)
#define T_PTS   (BB * NN)                  // 32768
#define T_W1    (T_PTS + 64 * 96)          // 38912
#define T_W2    (T_W1 + 64 * 64)           // 43008
#define T_W3    (T_W2 + 128 * 64)          // 51200
#define T_NXYZ  (T_W3 + BB * SS * 3)       // 75776
#define T_SIDX  (T_NXYZ + BB * SS)         // 83968 = 328*256
#define FEAT_B0 (T_SIDX / 256)             // 328: first feat-transpose block
#define NTILE   (BB * 2 * (NN / 32))       // 2048: 32ch x 32pt tiles
#define NBLK    (FEAT_B0 + NTILE)          // 2376 blocks (~9/CU: latency hiding)

// ---------------------------------------------------------------------------
// prep: pts4=(x,y,z,|x|^2) + coordinate+id-carrying per-cell bucket insert;
// bf16 weight transposes; coalesced new_xyz copy; samp_idx; feat [B][C][N]
// fp32 -> [B][N][C] bf16 via LDS-tiled transpose. Tiles shrunk 64x32 ->
// 32x32 (R8's 1024 tile-blocks = only 4/CU, latency-bound on the HBM row
// reads; 2048 blocks doubles the overlap). One wide launch.
// ---------------------------------------------------------------------------
__global__ __launch_bounds__(256) void prep_kernel(
        const float* __restrict__ xyz, const float* __restrict__ feat,
        const float* __restrict__ W1, const float* __restrict__ W2,
        const float* __restrict__ W3,
        float4* __restrict__ pts4, ushort* __restrict__ feat_nc,
        ushort* __restrict__ W1t, ushort* __restrict__ W2t,
        ushort* __restrict__ W3t,
        float* __restrict__ out_xyz, float* __restrict__ out_sidx,
        uint* __restrict__ counts, float4* __restrict__ lpts) {
    if (blockIdx.x >= FEAT_B0) {
        // ---- LDS-tiled feat transpose: one 32ch x 32pt tile per block ----
        __shared__ float tile[32][33];                 // +1 pad
        const int g = blockIdx.x - FEAT_B0;            // 0..2047
        const int b = g >> 10;
        const int rem = g & 1023;
        const int c0 = (rem >> 9) << 5;                // 0 or 32
        const int n0 = (rem & 511) << 5;
        const int t = threadIdx.x;
        const float* fb = feat + (size_t)b * CC * NN + (size_t)c0 * NN + n0;
        #pragma unroll
        for (int cc = 0; cc < 4; ++cc) {
            const int c = cc * 8 + (t >> 5);
            tile[c][t & 31] = fb[(size_t)c * NN + (t & 31)];
        }
        __syncthreads();
        if (t < 128) {
            const int p = t >> 2, gq = t & 3;          // 32 pts x 4 ch-octs
            uint u[4];
            #pragma unroll
            for (int q = 0; q < 4; ++q) {
                u[q] = (uint)f2bf(tile[gq * 8 + 2 * q][p]) |
                       ((uint)f2bf(tile[gq * 8 + 2 * q + 1][p]) << 16);
            }
            *(uint4*)(feat_nc + ((size_t)b * NN + n0 + p) * 64 + c0 + gq * 8) =
                make_uint4(u[0], u[1], u[2], u[3]);
        }
        return;
    }
    const int t = blockIdx.x * 256 + threadIdx.x;
    if (t < T_PTS) {
        const float* p = xyz + (size_t)t * 3;
        const float x = p[0], y = p[1], z = p[2];
        pts4[t] = make_float4(x, y, z, x * x + y * y + z * z);
        const int cell = (cellc(z) * GD + cellc(y)) * GD + cellc(x);
        const int b = t >> 14, n = t & (NN - 1);
        const uint rank = atomicAdd(&counts[(size_t)b * GC + cell], 1u);
        if (rank < CAPC) {
            const size_t slot = ((size_t)b * GC + cell) * CAPC + rank;
            lpts[slot] = make_float4(x, y, z, __int_as_float(n));
        }
    } else if (t < T_W1) {
        const int i = t - T_PTS;
        const int n = i / 96, k = i - n * 96;
        float v = 0.0f;
        if (k < 64) v = W1[(3 + k) * 64 + n];
        else if (k < 67) v = W1[(k - 64) * 64 + n];
        W1t[n * 96 + k] = f2bf(v);
    } else if (t < T_W2) {
        const int i = t - T_W1;
        const int n = i >> 6, k = i & 63;
        W2t[n * 64 + k] = f2bf(W2[k * 64 + n]);
    } else if (t < T_W3) {
        const int i = t - T_W2;
        const int n = i >> 6, k = i & 63;
        W3t[n * 64 + k] = f2bf(W3[k * 128 + n]);
    } else if (t < T_NXYZ) {
        const int i = t - T_W3;              // new_xyz = xyz[:, :SS] copy
        const int b = i / (SS * 3), j = i - b * (SS * 3);
        out_xyz[i] = xyz[(size_t)b * NN * 3 + j];
    } else if (t < T_SIDX) {
        const int i = t - T_NXYZ;
        out_sidx[i] = (float)(i & (SS - 1));
    }
}

// per-lane 27-way segment select (pre/A constant-indexed, rule-#20 safe)
#define ADJ27(gq, adjv) do { adjv = A[0];                                   \
    _Pragma("unroll")                                                       \
    for (int k_ = 1; k_ < 27; ++k_) adjv = ((gq) >= pre[k_]) ? A[k_] : adjv;\
} while (0)

// ---------------------------------------------------------------------------
// fused: one wave = one centroid, 2-WAVE blocks (128 thr, grid 4096).
// R8's 4-wave blocks retire at the max of 4 independent centroids' variable
// BQ times; 2-wave halves that coupling and doubles queue depth to 16
// blocks/CU (12 resident by LDS) — targets the measured 34% occupancy /
// 65%-stall regime. BQ body (pruned cells, 2-deep pipeline, ballot-popcount
// 32-smallest select), gather, and MLP are byte-identical to passing R8.
// ---------------------------------------------------------------------------
__global__ __launch_bounds__(128) void fused_kernel(
        const float4* __restrict__ pts4, const ushort* __restrict__ feat_nc,
        const uint* __restrict__ counts, const float4* __restrict__ lpts,
        const ushort* __restrict__ W1t, const ushort* __restrict__ W2t,
        const ushort* __restrict__ W3t,
        const float* __restrict__ b1, const float* __restrict__ b2,
        const float* __restrict__ b3, float* __restrict__ out_feat) {
    const int w = threadIdx.x >> 6, lane = threadIdx.x & 63;
    const int quad = lane >> 4, mrow = lane & 15;
    const int m = lane & 31, half = lane >> 5;

    __shared__ __align__(16) ushort ldsA[2][32 * 104];   // hits -> g -> h1 -> h2 (+tails)
    ushort* gbuf = ldsA[w];
    int* hit = (int*)gbuf;                               // 2KB bq scratch (CAP ints)

    const int xcd = blockIdx.x & 7;
    const int slot = blockIdx.x >> 3;              // 0..511
    const int b = xcd >> 2;
    const int s0 = ((xcd & 3) * 512 + slot) * 2;   // block's 2-s tile
    const int s = s0 + w;

    const float4* pb = pts4 + (size_t)b * NN;
    const ushort* fbase = feat_nc + (size_t)b * NN * 64;
    const unsigned long long ltmask = (1ull << lane) - 1ull;

    // ================= ball query via pruned cell buckets =================
    {
        const float4 c = pb[s];
        const int cx = cellc(c.x), cy = cellc(c.y), cz = cellc(c.z);
        const uint* cntb = counts + (size_t)b * GC;
        const float4* lptsb = lpts + (size_t)b * GC * CAPC;

        int pre[28], A[27];
        pre[0] = 0;
        #pragma unroll
        for (int e = 0; e < 27; ++e) {
            const int z = cz + e / 9 - 1;
            const int y = cy + (e / 3) % 3 - 1;
            const int x = cx + e % 3 - 1;
            const bool ok = ((unsigned)z < GD) && ((unsigned)y < GD) && ((unsigned)x < GD);
            const int ci = (z * GD + y) * GD + x;
            // exact cell-box vs ball test (edge cells unbounded on clamped side)
            const float bx0 = (x <= 0)      ? -1e30f : (x - 12) * 0.4f;
            const float bx1 = (x >= GD - 1) ?  1e30f : (x - 11) * 0.4f;
            const float by0 = (y <= 0)      ? -1e30f : (y - 12) * 0.4f;
            const float by1 = (y >= GD - 1) ?  1e30f : (y - 11) * 0.4f;
            const float bz0 = (z <= 0)      ? -1e30f : (z - 12) * 0.4f;
            const float bz1 = (z >= GD - 1) ?  1e30f : (z - 11) * 0.4f;
            const float dx = fmaxf(fmaxf(bx0 - c.x, c.x - bx1), 0.0f);
            const float dy = fmaxf(fmaxf(by0 - c.y, c.y - by1), 0.0f);
            const float dz = fmaxf(fmaxf(bz0 - c.z, c.z - bz1), 0.0f);
            const bool reach = (dx * dx + dy * dy + dz * dz) < (R2 + 1e-3f);
            int cn = (ok && reach) ? (int)cntb[ok ? ci : 0] : 0;
            cn = cn < CAPC ? cn : CAPC;          // overflow clamp (memory safety)
            A[e] = ci * CAPC - pre[e];
            pre[e + 1] = pre[e] + cn;
        }
        const int tot = pre[27];

        int cnt = 0;
        float4 pc;
        {
            const int g = lane;
            int adj; ADJ27(g, adj);
            pc = lptsb[(g < tot) ? (g + adj) : 0];
        }
        for (int g0 = 0; g0 < tot; g0 += 64) {
            float4 pn;                           // prefetch next 64 entries
            {
                const int gn = g0 + 64 + lane;
                int adjn; ADJ27(gn, adjn);
                pn = lptsb[(gn < tot) ? (gn + adjn) : 0];
            }
            const bool act = (g0 + lane) < tot;
            const float pw = pc.x * pc.x + pc.y * pc.y + pc.z * pc.z;
            const float d = c.w + pw - 2.0f * (c.x * pc.x + c.y * pc.y + c.z * pc.z);
            const bool h = act && (d < R2);
            const unsigned long long mk = __ballot(h);
            if (h) {
                const int pp = cnt + __popcll(mk & ltmask);
                if (pp < CAP) hit[pp] = __float_as_int(pc.w);
            }
            cnt += (int)__popcll(mk);
            pc = pn;
        }

        // ---- keep the 32 smallest original indices (set-equivalent to the
        // reference "first nsample in index order"; maxpool ignores order) ----
        if (cnt > KK) {
            const int stored = cnt < CAP ? cnt : CAP;
            int v[CAPL];
            #pragma unroll
            for (int j = 0; j < CAPL; ++j) {
                const int q = j * 64 + lane;
                const int val = hit[q];            // within allocated LDS
                v[j] = (q < stored) ? val : 0x7fffffff;
            }
            int lo = 0, hi = NN - 1;
            while (lo < hi) {                      // wave-uniform, <=14 iters
                const int mid = (lo + hi) >> 1;
                int cle = 0;
                #pragma unroll
                for (int j = 0; j < CAPL; ++j)
                    if (j * 64 < stored)           // wave-uniform chunk gate
                        cle += (int)__popcll(__ballot(v[j] <= mid));
                if (cle >= KK) hi = mid; else lo = mid + 1;
            }
            int pos = 0;                           // exactly KK selected (ids unique)
            #pragma unroll
            for (int j = 0; j < CAPL; ++j) {
                if (j * 64 < stored) {
                    const bool sel = v[j] <= lo;
                    const unsigned long long mk = __ballot(sel);
                    if (sel) hit[pos + __popcll(mk & ltmask)] = v[j];
                    pos += (int)__popcll(mk);
                }
            }
        } else if (lane < KK) {
            const int vv = (cnt == 0) ? 0 : ((lane < cnt) ? hit[lane] : hit[0]);
            hit[lane] = vv;
        }
    }

    // ================= gather: sid (LDS) -> rows -> LDS =================
    {
        const int sid = hit[m];                  // wave-private, program order
        const ushort* src = fbase + (size_t)sid * 64 + half * 32;
        ushort* dst = gbuf + m * 104 + half * 32;
        uint4 rows[4];
        #pragma unroll
        for (int i = 0; i < 4; ++i) rows[i] = *(const uint4*)(src + i * 8);
        const float4 p = pb[sid];
        const float4 cc = pb[s];
        #pragma unroll
        for (int i = 0; i < 4; ++i) *(uint4*)(dst + i * 8) = rows[i];
        if (half == 0) {
            bf16x8 rel = {(__bf16)(p.x - cc.x), (__bf16)(p.y - cc.y),
                          (__bf16)(p.z - cc.z), (__bf16)0.f,
                          (__bf16)0.f, (__bf16)0.f, (__bf16)0.f, (__bf16)0.f};
            *(bf16x8*)(gbuf + m * 104 + 64) = rel;
            *(uint4*)(gbuf + m * 104 + 88) = make_uint4(0, 0, 0, 0);
        } else {
            *(uint4*)(gbuf + m * 104 + 72) = make_uint4(0, 0, 0, 0);
            *(uint4*)(gbuf + m * 104 + 80) = make_uint4(0, 0, 0, 0);
        }
    }

    // ================= layer 1: [32x96]x[96x64] =================
    {
        f32x4 acc[2][4];
        #pragma unroll
        for (int nt = 0; nt < 4; ++nt) {
            const float bv = b1[nt * 16 + mrow];
            acc[0][nt] = (f32x4){bv, bv, bv, bv};
            acc[1][nt] = acc[0][nt];
        }
        #pragma unroll
        for (int ks = 0; ks < 3; ++ks) {
            const bf16x8 a0 = *(const bf16x8*)(gbuf + mrow * 104 + ks * 32 + quad * 8);
            const bf16x8 a1 = *(const bf16x8*)(gbuf + (16 + mrow) * 104 + ks * 32 + quad * 8);
            #pragma unroll
            for (int nt = 0; nt < 4; ++nt) {
                const bf16x8 wf = *(const bf16x8*)(W1t + (nt * 16 + mrow) * 96 + ks * 32 + quad * 8);
                acc[0][nt] = MFMA(a0, wf, acc[0][nt]);
                acc[1][nt] = MFMA(a1, wf, acc[1][nt]);
            }
        }
        #pragma unroll
        for (int mt = 0; mt < 2; ++mt)
            #pragma unroll
            for (int nt = 0; nt < 4; ++nt)
                #pragma unroll
                for (int r = 0; r < 4; ++r)
                    gbuf[(mt * 16 + quad * 4 + r) * 104 + nt * 16 + mrow] =
                        f2bf(fmaxf(acc[mt][nt][r], 0.0f));
    }

    // ================= layer 2: [32x64]x[64x64] =================
    {
        f32x4 acc[2][4];
        #pragma unroll
        for (int nt = 0; nt < 4; ++nt) {
            const float bv = b2[nt * 16 + mrow];
            acc[0][nt] = (f32x4){bv, bv, bv, bv};
            acc[1][nt] = acc[0][nt];
        }
        #pragma unroll
        for (int ks = 0; ks < 2; ++ks) {
            const bf16x8 a0 = *(const bf16x8*)(gbuf + mrow * 104 + ks * 32 + quad * 8);
            const bf16x8 a1 = *(const bf16x8*)(gbuf + (16 + mrow) * 104 + ks * 32 + quad * 8);
            #pragma unroll
            for (int nt = 0; nt < 4; ++nt) {
                const bf16x8 wf = *(const bf16x8*)(W2t + (nt * 16 + mrow) * 64 + ks * 32 + quad * 8);
                acc[0][nt] = MFMA(a0, wf, acc[0][nt]);
                acc[1][nt] = MFMA(a1, wf, acc[1][nt]);
            }
        }
        #pragma unroll
        for (int mt = 0; mt < 2; ++mt)
            #pragma unroll
            for (int nt = 0; nt < 4; ++nt)
                #pragma unroll
                for (int r = 0; r < 4; ++r)
                    gbuf[(mt * 16 + quad * 4 + r) * 104 + nt * 16 + mrow] =
                        f2bf(fmaxf(acc[mt][nt][r], 0.0f));
    }

    // ============ layer 3: [32x64]x[64x128] two n-halves + maxpool ==========
    // maxpool results go to the free 16B tail of each gbuf row (bytes 192-207;
    // MFMA reads touch only cols 0-63).
    #pragma unroll
    for (int nh = 0; nh < 2; ++nh) {
        f32x4 acc[2][4];
        #pragma unroll
        for (int ntl = 0; ntl < 4; ++ntl) {
            const float bv = b3[(nh * 4 + ntl) * 16 + mrow];
            acc[0][ntl] = (f32x4){bv, bv, bv, bv};
            acc[1][ntl] = acc[0][ntl];
        }
        #pragma unroll
        for (int ks = 0; ks < 2; ++ks) {
            const bf16x8 a0 = *(const bf16x8*)(gbuf + mrow * 104 + ks * 32 + quad * 8);
            const bf16x8 a1 = *(const bf16x8*)(gbuf + (16 + mrow) * 104 + ks * 32 + quad * 8);
            #pragma unroll
            for (int ntl = 0; ntl < 4; ++ntl) {
                const bf16x8 wf = *(const bf16x8*)(
                    W3t + ((nh * 4 + ntl) * 16 + mrow) * 64 + ks * 32 + quad * 8);
                acc[0][ntl] = MFMA(a0, wf, acc[0][ntl]);
                acc[1][ntl] = MFMA(a1, wf, acc[1][ntl]);
            }
        }
        #pragma unroll
        for (int ntl = 0; ntl < 4; ++ntl) {
            const f32x4 v0 = acc[0][ntl], v1 = acc[1][ntl];
            float mx = fmaxf(fmaxf(v0[0], v0[1]), fmaxf(v0[2], v0[3]));
            mx = fmaxf(mx, fmaxf(fmaxf(v1[0], v1[1]), fmaxf(v1[2], v1[3])));
            mx = fmaxf(mx, __shfl_xor(mx, 16));
            mx = fmaxf(mx, __shfl_xor(mx, 32));
            mx = fmaxf(mx, 0.0f);
            if (quad == 0) {
                const int ch = (nh * 4 + ntl) * 16 + mrow;
                *(float*)((char*)gbuf + (ch >> 2) * 208 + 192 + (ch & 3) * 4) = mx;
            }
        }
    }
    __syncthreads();

    // ---- epilogue: 128 ch x 2 s, float2 per thread (reads both waves' tails)
    {
        const int ch = threadIdx.x;                // 0..127
        const int tb = (ch >> 2) * 208 + 192 + (ch & 3) * 4;
        const float v0 = *(const float*)((const char*)ldsA[0] + tb);
        const float v1 = *(const float*)((const char*)ldsA[1] + tb);
        float* dst = out_feat + ((size_t)b * 128 + ch) * SS + s0;
        *(float2*)dst = make_float2(v0, v1);
    }
}

// ---------------------------------------------------------------------------
extern "C" void kernel_launch(void* const* d_in, const int* in_sizes, int n_in,
                              void* d_out, int out_size, void* d_ws, size_t ws_size,
                              hipStream_t stream) {
    const float* xyz  = (const float*)d_in[0];
    const float* feat = (const float*)d_in[1];
    const float* W1   = (const float*)d_in[2];
    const float* b1   = (const float*)d_in[3];
    const float* W2   = (const float*)d_in[4];
    const float* b2   = (const float*)d_in[5];
    const float* W3   = (const float*)d_in[6];
    const float* b3   = (const float*)d_in[7];

    float* out      = (float*)d_out;
    float* out_xyz  = out;                               // [2,4096,3]
    float* out_feat = out + (size_t)BB * SS * 3;         // [2,128,4096]
    float* out_sidx = out_feat + (size_t)BB * 128 * SS;  // [2,4096]

    char* ws = (char*)d_ws;
    float4* pts4    = (float4*)(ws + WS_PTS4);
    ushort* feat_nc = (ushort*)(ws + WS_FEAT);
    ushort* W1t     = (ushort*)(ws + WS_W1T);
    ushort* W2t     = (ushort*)(ws + WS_W2T);
    ushort* W3t     = (ushort*)(ws + WS_W3T);
    uint*   counts  = (uint*)(ws + WS_CNT);
    float4* lpts    = (float4*)(ws + WS_LPTS);

    hipMemsetAsync(counts, 0, (size_t)BB * GC * 4, stream);
    prep_kernel<<<NBLK, 256, 0, stream>>>(
        xyz, feat, W1, W2, W3, pts4, feat_nc, W1t, W2t, W3t, out_xyz, out_sidx,
        counts, lpts);
    fused_kernel<<<BB * SS / 2, 128, 0, stream>>>(pts4, feat_nc, counts, lpts,
                                                  W1t, W2t, W3t, b1, b2, b3,
                                                  out_feat);
}

// Round 10
// 140.519 us; speedup vs baseline: 1.0245x; 1.0245x over previous
//
#include <hip/hip_runtime.h>

#define BB 2
#define NN 16384
#define CC 64
#define SS 4096
#define KK 32
#define R2 0.16f   // RADIUS^2

// spatial grid: cell = RADIUS, 24^3 cells covering [-4.8, 4.8] (clamped; the
// clamp is monotone so the 3x3x3 neighborhood remains a superset of the ball
// for ANY input magnitude — tail points just pile into edge cells)
#define GD   24
#define GC   (GD * GD * GD)       // 13824 cells per batch
#define CAPC 112                  // per-cell bucket capacity (center cell ~66)
#define CAP  512                  // per-wave hit-list capacity (max expected ~360)
#define CAPL (CAP / 64)           // 8 register chunks for selection

typedef __bf16 bf16x8 __attribute__((ext_vector_type(8)));
typedef float  f32x4  __attribute__((ext_vector_type(4)));

#define MFMA(a, b, c) __builtin_amdgcn_mfma_f32_16x16x32_bf16((a), (b), (c), 0, 0, 0)

static __device__ __forceinline__ ushort f2bf(float f) {
    __bf16 h = (__bf16)f;
    return *(ushort*)&h;
}

static __device__ __forceinline__ int cellc(float x) {
    int i = (int)floorf(x * 2.5f + 12.0f);
    return i < 0 ? 0 : (i > GD - 1 ? GD - 1 : i);
}

// workspace section offsets (bytes), all 16B aligned
#define WS_PTS4   0          // pts4:    2*16384*16    =   524,288
#define WS_FEAT   524288     // feat_nc: 2*16384*64*2  = 4,194,304
#define WS_W1T    4718592    // 64*96*2   = 12,288
#define WS_W2T    4730880    // 64*64*2   =  8,192
#define WS_W3T    4739072    // 128*64*2  = 16,384
#define WS_CNT    4755456    // counts: 2*13824*4 = 110,592
#define WS_LPTS   4866048    // coord+id buckets: 2*13824*112*16 = 49,545,216
                             // (end 54,411,264; id packed in .w — no list[])

// prep index ranges (block-granular: T_SIDX = 328 blocks exactly)
#define T_PTS   (BB * NN)                  // 32768
#define T_W1    (T_PTS + 64 * 96)          // 38912
#define T_W2    (T_W1 + 64 * 64)           // 43008
#define T_W3    (T_W2 + 128 * 64)          // 51200
#define T_NXYZ  (T_W3 + BB * SS * 3)       // 75776
#define T_SIDX  (T_NXYZ + BB * SS)         // 83968 = 328*256
#define FEAT_B0 (T_SIDX / 256)             // 328: first feat-transpose block
#define NBLK    (FEAT_B0 + BB * (NN / 32)) // 328 + 1024 = 1352 blocks

// ---------------------------------------------------------------------------
// prep: pts4=(x,y,z,|x|^2) + coordinate+id-carrying per-cell bucket insert;
// bf16 weight transposes; coalesced new_xyz copy; samp_idx; feat [B][C][N]
// fp32 -> [B][N][C] bf16 via LDS-tiled transpose (blocks >= FEAT_B0). One
// wide launch. (Exact R8 structure — the session-best total.)
// ---------------------------------------------------------------------------
__global__ __launch_bounds__(256) void prep_kernel(
        const float* __restrict__ xyz, const float* __restrict__ feat,
        const float* __restrict__ W1, const float* __restrict__ W2,
        const float* __restrict__ W3,
        float4* __restrict__ pts4, ushort* __restrict__ feat_nc,
        ushort* __restrict__ W1t, ushort* __restrict__ W2t,
        ushort* __restrict__ W3t,
        float* __restrict__ out_xyz, float* __restrict__ out_sidx,
        uint* __restrict__ counts, float4* __restrict__ lpts) {
    if (blockIdx.x >= FEAT_B0) {
        // ---- LDS-tiled feat transpose: one 64ch x 32pt tile per block ----
        __shared__ float tile[64][33];                 // +1 pad
        const int g = blockIdx.x - FEAT_B0;            // 0..1023
        const int b = g >> 9, n0 = (g & 511) << 5;
        const int t = threadIdx.x;
        const float* fb = feat + (size_t)b * CC * NN + n0;
        #pragma unroll
        for (int cc = 0; cc < 8; ++cc) {
            const int c = cc * 8 + (t >> 5);
            tile[c][t & 31] = fb[(size_t)c * NN + (t & 31)];
        }
        __syncthreads();
        const int p = t >> 3, c8 = t & 7;
        uint u[4];
        #pragma unroll
        for (int q = 0; q < 4; ++q) {
            u[q] = (uint)f2bf(tile[c8 * 8 + 2 * q][p]) |
                   ((uint)f2bf(tile[c8 * 8 + 2 * q + 1][p]) << 16);
        }
        *(uint4*)(feat_nc + ((size_t)b * NN + n0 + p) * 64 + c8 * 8) =
            make_uint4(u[0], u[1], u[2], u[3]);
        return;
    }
    const int t = blockIdx.x * 256 + threadIdx.x;
    if (t < T_PTS) {
        const float* p = xyz + (size_t)t * 3;
        const float x = p[0], y = p[1], z = p[2];
        pts4[t] = make_float4(x, y, z, x * x + y * y + z * z);
        const int cell = (cellc(z) * GD + cellc(y)) * GD + cellc(x);
        const int b = t >> 14, n = t & (NN - 1);
        const uint rank = atomicAdd(&counts[(size_t)b * GC + cell], 1u);
        if (rank < CAPC) {
            const size_t slot = ((size_t)b * GC + cell) * CAPC + rank;
            lpts[slot] = make_float4(x, y, z, __int_as_float(n));
        }
    } else if (t < T_W1) {
        const int i = t - T_PTS;
        const int n = i / 96, k = i - n * 96;
        float v = 0.0f;
        if (k < 64) v = W1[(3 + k) * 64 + n];
        else if (k < 67) v = W1[(k - 64) * 64 + n];
        W1t[n * 96 + k] = f2bf(v);
    } else if (t < T_W2) {
        const int i = t - T_W1;
        const int n = i >> 6, k = i & 63;
        W2t[n * 64 + k] = f2bf(W2[k * 64 + n]);
    } else if (t < T_W3) {
        const int i = t - T_W2;
        const int n = i >> 6, k = i & 63;
        W3t[n * 64 + k] = f2bf(W3[k * 128 + n]);
    } else if (t < T_NXYZ) {
        const int i = t - T_W3;              // new_xyz = xyz[:, :SS] copy
        const int b = i / (SS * 3), j = i - b * (SS * 3);
        out_xyz[i] = xyz[(size_t)b * NN * 3 + j];
    } else if (t < T_SIDX) {
        const int i = t - T_NXYZ;
        out_sidx[i] = (float)(i & (SS - 1));
    }
}

// per-lane 27-way segment select (pre/A constant-indexed, rule-#20 safe)
#define ADJ27(gq, adjv) do { adjv = A[0];                                   \
    _Pragma("unroll")                                                       \
    for (int k_ = 1; k_ < 27; ++k_) adjv = ((gq) >= pre[k_]) ? A[k_] : adjv;\
} while (0)

// ---------------------------------------------------------------------------
// fused: one wave = one centroid, 4-wave blocks (exact R8 structure — the
// best-measured config). Ball query over the 3x3x3 neighbor cells with
// PER-AXIS-FACTORIZED exact pruning: 9 axis-distance values (3 offsets x 3
// axes, edge cells unbounded on clamped side) replace 27 full box tests —
// same pruned set, ~1/4 the setup VALU. Flattened candidate loop, 2-deep
// load pipeline, ballot-popcount 32-smallest select (preload chunk-gated).
// Gather + 3-layer MLP + maxpool in gbuf tails — byte-identical to R8.
// ---------------------------------------------------------------------------
__global__ __launch_bounds__(256, 2) void fused_kernel(
        const float4* __restrict__ pts4, const ushort* __restrict__ feat_nc,
        const uint* __restrict__ counts, const float4* __restrict__ lpts,
        const ushort* __restrict__ W1t, const ushort* __restrict__ W2t,
        const ushort* __restrict__ W3t,
        const float* __restrict__ b1, const float* __restrict__ b2,
        const float* __restrict__ b3, float* __restrict__ out_feat) {
    const int w = threadIdx.x >> 6, lane = threadIdx.x & 63;
    const int quad = lane >> 4, mrow = lane & 15;
    const int m = lane & 31, half = lane >> 5;

    __shared__ __align__(16) ushort ldsA[4][32 * 104];   // hits -> g -> h1 -> h2 (+tails)
    ushort* gbuf = ldsA[w];
    int* hit = (int*)gbuf;                               // 2KB bq scratch (CAP ints)

    const int xcd = blockIdx.x & 7;
    const int slot = blockIdx.x >> 3;              // 0..255
    const int b = xcd >> 2;
    const int s0 = ((xcd & 3) * 256 + slot) * 4;   // block's 4-s tile
    const int s = s0 + w;

    const float4* pb = pts4 + (size_t)b * NN;
    const ushort* fbase = feat_nc + (size_t)b * NN * 64;
    const unsigned long long ltmask = (1ull << lane) - 1ull;

    // ================= ball query via pruned cell buckets =================
    {
        const float4 c = pb[s];
        const int cx = cellc(c.x), cy = cellc(c.y), cz = cellc(c.z);
        const uint* cntb = counts + (size_t)b * GC;
        const float4* lptsb = lpts + (size_t)b * GC * CAPC;

        // per-axis squared distances to the 3 candidate cells (offsets -1,0,+1)
        // and validity; constant-indexed arrays (rule-#20 safe).
        float d2x[3], d2y[3], d2z[3];
        bool vx[3], vy[3], vz[3];
        #pragma unroll
        for (int o = 0; o < 3; ++o) {
            {
                const int X = cx + o - 1;
                vx[o] = ((unsigned)X < GD);
                const float lo = (X <= 0)      ? -1e30f : (X - 12) * 0.4f;
                const float hi = (X >= GD - 1) ?  1e30f : (X - 11) * 0.4f;
                const float d = fmaxf(fmaxf(lo - c.x, c.x - hi), 0.0f);
                d2x[o] = d * d;
            }
            {
                const int Y = cy + o - 1;
                vy[o] = ((unsigned)Y < GD);
                const float lo = (Y <= 0)      ? -1e30f : (Y - 12) * 0.4f;
                const float hi = (Y >= GD - 1) ?  1e30f : (Y - 11) * 0.4f;
                const float d = fmaxf(fmaxf(lo - c.y, c.y - hi), 0.0f);
                d2y[o] = d * d;
            }
            {
                const int Z = cz + o - 1;
                vz[o] = ((unsigned)Z < GD);
                const float lo = (Z <= 0)      ? -1e30f : (Z - 12) * 0.4f;
                const float hi = (Z >= GD - 1) ?  1e30f : (Z - 11) * 0.4f;
                const float d = fmaxf(fmaxf(lo - c.z, c.z - hi), 0.0f);
                d2z[o] = d * d;
            }
        }

        int pre[28], A[27];
        pre[0] = 0;
        #pragma unroll
        for (int e = 0; e < 27; ++e) {
            const int ez = e / 9, ey = (e / 3) % 3, ex = e % 3;  // const per e
            const int ci = ((cz + ez - 1) * GD + (cy + ey - 1)) * GD + (cx + ex - 1);
            const bool ok = vx[ex] && vy[ey] && vz[ez];
            const bool reach = (d2x[ex] + d2y[ey] + d2z[ez]) < (R2 + 1e-3f);
            int cn = (ok && reach) ? (int)cntb[ok ? ci : 0] : 0;
            cn = cn < CAPC ? cn : CAPC;          // overflow clamp (memory safety)
            A[e] = ci * CAPC - pre[e];
            pre[e + 1] = pre[e] + cn;
        }
        const int tot = pre[27];

        int cnt = 0;
        float4 pc;
        {
            const int g = lane;
            int adj; ADJ27(g, adj);
            pc = lptsb[(g < tot) ? (g + adj) : 0];
        }
        for (int g0 = 0; g0 < tot; g0 += 64) {
            float4 pn;                           // prefetch next 64 entries
            {
                const int gn = g0 + 64 + lane;
                int adjn; ADJ27(gn, adjn);
                pn = lptsb[(gn < tot) ? (gn + adjn) : 0];
            }
            const bool act = (g0 + lane) < tot;
            const float pw = pc.x * pc.x + pc.y * pc.y + pc.z * pc.z;
            const float d = c.w + pw - 2.0f * (c.x * pc.x + c.y * pc.y + c.z * pc.z);
            const bool h = act && (d < R2);
            const unsigned long long mk = __ballot(h);
            if (h) {
                const int pp = cnt + __popcll(mk & ltmask);
                if (pp < CAP) hit[pp] = __float_as_int(pc.w);
            }
            cnt += (int)__popcll(mk);
            pc = pn;
        }

        // ---- keep the 32 smallest original indices (set-equivalent to the
        // reference "first nsample in index order"; maxpool ignores order) ----
        if (cnt > KK) {
            const int stored = cnt < CAP ? cnt : CAP;
            int v[CAPL];
            #pragma unroll
            for (int j = 0; j < CAPL; ++j) {
                if (j * 64 < stored) {             // chunk-gated preload
                    const int q = j * 64 + lane;
                    v[j] = (q < stored) ? hit[q] : 0x7fffffff;
                } else {
                    v[j] = 0x7fffffff;
                }
            }
            int lo = 0, hi = NN - 1;
            while (lo < hi) {                      // wave-uniform, <=14 iters
                const int mid = (lo + hi) >> 1;
                int cle = 0;
                #pragma unroll
                for (int j = 0; j < CAPL; ++j)
                    if (j * 64 < stored)           // wave-uniform chunk gate
                        cle += (int)__popcll(__ballot(v[j] <= mid));
                if (cle >= KK) hi = mid; else lo = mid + 1;
            }
            int pos = 0;                           // exactly KK selected (ids unique)
            #pragma unroll
            for (int j = 0; j < CAPL; ++j) {
                if (j * 64 < stored) {
                    const bool sel = v[j] <= lo;
                    const unsigned long long mk = __ballot(sel);
                    if (sel) hit[pos + __popcll(mk & ltmask)] = v[j];
                    pos += (int)__popcll(mk);
                }
            }
        } else if (lane < KK) {
            const int vv = (cnt == 0) ? 0 : ((lane < cnt) ? hit[lane] : hit[0]);
            hit[lane] = vv;
        }
    }

    // ================= gather: sid (LDS) -> rows -> LDS =================
    {
        const int sid = hit[m];                  // wave-private, program order
        const ushort* src = fbase + (size_t)sid * 64 + half * 32;
        ushort* dst = gbuf + m * 104 + half * 32;
        uint4 rows[4];
        #pragma unroll
        for (int i = 0; i < 4; ++i) rows[i] = *(const uint4*)(src + i * 8);
        const float4 p = pb[sid];
        const float4 cc = pb[s];
        #pragma unroll
        for (int i = 0; i < 4; ++i) *(uint4*)(dst + i * 8) = rows[i];
        if (half == 0) {
            bf16x8 rel = {(__bf16)(p.x - cc.x), (__bf16)(p.y - cc.y),
                          (__bf16)(p.z - cc.z), (__bf16)0.f,
                          (__bf16)0.f, (__bf16)0.f, (__bf16)0.f, (__bf16)0.f};
            *(bf16x8*)(gbuf + m * 104 + 64) = rel;
            *(uint4*)(gbuf + m * 104 + 88) = make_uint4(0, 0, 0, 0);
        } else {
            *(uint4*)(gbuf + m * 104 + 72) = make_uint4(0, 0, 0, 0);
            *(uint4*)(gbuf + m * 104 + 80) = make_uint4(0, 0, 0, 0);
        }
    }

    // ================= layer 1: [32x96]x[96x64] =================
    {
        f32x4 acc[2][4];
        #pragma unroll
        for (int nt = 0; nt < 4; ++nt) {
            const float bv = b1[nt * 16 + mrow];
            acc[0][nt] = (f32x4){bv, bv, bv, bv};
            acc[1][nt] = acc[0][nt];
        }
        #pragma unroll
        for (int ks = 0; ks < 3; ++ks) {
            const bf16x8 a0 = *(const bf16x8*)(gbuf + mrow * 104 + ks * 32 + quad * 8);
            const bf16x8 a1 = *(const bf16x8*)(gbuf + (16 + mrow) * 104 + ks * 32 + quad * 8);
            #pragma unroll
            for (int nt = 0; nt < 4; ++nt) {
                const bf16x8 wf = *(const bf16x8*)(W1t + (nt * 16 + mrow) * 96 + ks * 32 + quad * 8);
                acc[0][nt] = MFMA(a0, wf, acc[0][nt]);
                acc[1][nt] = MFMA(a1, wf, acc[1][nt]);
            }
        }
        #pragma unroll
        for (int mt = 0; mt < 2; ++mt)
            #pragma unroll
            for (int nt = 0; nt < 4; ++nt)
                #pragma unroll
                for (int r = 0; r < 4; ++r)
                    gbuf[(mt * 16 + quad * 4 + r) * 104 + nt * 16 + mrow] =
                        f2bf(fmaxf(acc[mt][nt][r], 0.0f));
    }

    // ================= layer 2: [32x64]x[64x64] =================
    {
        f32x4 acc[2][4];
        #pragma unroll
        for (int nt = 0; nt < 4; ++nt) {
            const float bv = b2[nt * 16 + mrow];
            acc[0][nt] = (f32x4){bv, bv, bv, bv};
            acc[1][nt] = acc[0][nt];
        }
        #pragma unroll
        for (int ks = 0; ks < 2; ++ks) {
            const bf16x8 a0 = *(const bf16x8*)(gbuf + mrow * 104 + ks * 32 + quad * 8);
            const bf16x8 a1 = *(const bf16x8*)(gbuf + (16 + mrow) * 104 + ks * 32 + quad * 8);
            #pragma unroll
            for (int nt = 0; nt < 4; ++nt) {
                const bf16x8 wf = *(const bf16x8*)(W2t + (nt * 16 + mrow) * 64 + ks * 32 + quad * 8);
                acc[0][nt] = MFMA(a0, wf, acc[0][nt]);
                acc[1][nt] = MFMA(a1, wf, acc[1][nt]);
            }
        }
        #pragma unroll
        for (int mt = 0; mt < 2; ++mt)
            #pragma unroll
            for (int nt = 0; nt < 4; ++nt)
                #pragma unroll
                for (int r = 0; r < 4; ++r)
                    gbuf[(mt * 16 + quad * 4 + r) * 104 + nt * 16 + mrow] =
                        f2bf(fmaxf(acc[mt][nt][r], 0.0f));
    }

    // ============ layer 3: [32x64]x[64x128] two n-halves + maxpool ==========
    // maxpool results go to the free 16B tail of each gbuf row (bytes 192-207;
    // MFMA reads touch only cols 0-63).
    #pragma unroll
    for (int nh = 0; nh < 2; ++nh) {
        f32x4 acc[2][4];
        #pragma unroll
        for (int ntl = 0; ntl < 4; ++ntl) {
            const float bv = b3[(nh * 4 + ntl) * 16 + mrow];
            acc[0][ntl] = (f32x4){bv, bv, bv, bv};
            acc[1][ntl] = acc[0][ntl];
        }
        #pragma unroll
        for (int ks = 0; ks < 2; ++ks) {
            const bf16x8 a0 = *(const bf16x8*)(gbuf + mrow * 104 + ks * 32 + quad * 8);
            const bf16x8 a1 = *(const bf16x8*)(gbuf + (16 + mrow) * 104 + ks * 32 + quad * 8);
            #pragma unroll
            for (int ntl = 0; ntl < 4; ++ntl) {
                const bf16x8 wf = *(const bf16x8*)(
                    W3t + ((nh * 4 + ntl) * 16 + mrow) * 64 + ks * 32 + quad * 8);
                acc[0][ntl] = MFMA(a0, wf, acc[0][ntl]);
                acc[1][ntl] = MFMA(a1, wf, acc[1][ntl]);
            }
        }
        #pragma unroll
        for (int ntl = 0; ntl < 4; ++ntl) {
            const f32x4 v0 = acc[0][ntl], v1 = acc[1][ntl];
            float mx = fmaxf(fmaxf(v0[0], v0[1]), fmaxf(v0[2], v0[3]));
            mx = fmaxf(mx, fmaxf(fmaxf(v1[0], v1[1]), fmaxf(v1[2], v1[3])));
            mx = fmaxf(mx, __shfl_xor(mx, 16));
            mx = fmaxf(mx, __shfl_xor(mx, 32));
            mx = fmaxf(mx, 0.0f);
            if (quad == 0) {
                const int ch = (nh * 4 + ntl) * 16 + mrow;
                *(float*)((char*)gbuf + (ch >> 2) * 208 + 192 + (ch & 3) * 4) = mx;
            }
        }
    }
    __syncthreads();

    // ---- epilogue: 128 ch x 4 s, float2 per thread (reads gbuf tails) ----
    {
        const int ch = threadIdx.x & 127;
        const int hf = threadIdx.x >> 7;           // 0/1
        const int tb = (ch >> 2) * 208 + 192 + (ch & 3) * 4;
        const float v0 = *(const float*)((const char*)ldsA[hf * 2] + tb);
        const float v1 = *(const float*)((const char*)ldsA[hf * 2 + 1] + tb);
        float* dst = out_feat + ((size_t)b * 128 + ch) * SS + s0 + hf * 2;
        *(float2*)dst = make_float2(v0, v1);
    }
}

// ---------------------------------------------------------------------------
extern "C" void kernel_launch(void* const* d_in, const int* in_sizes, int n_in,
                              void* d_out, int out_size, void* d_ws, size_t ws_size,
                              hipStream_t stream) {
    const float* xyz  = (const float*)d_in[0];
    const float* feat = (const float*)d_in[1];
    const float* W1   = (const float*)d_in[2];
    const float* b1   = (const float*)d_in[3];
    const float* W2   = (const float*)d_in[4];
    const float* b2   = (const float*)d_in[5];
    const float* W3   = (const float*)d_in[6];
    const float* b3   = (const float*)d_in[7];

    float* out      = (float*)d_out;
    float* out_xyz  = out;                               // [2,4096,3]
    float* out_feat = out + (size_t)BB * SS * 3;         // [2,128,4096]
    float* out_sidx = out_feat + (size_t)BB * 128 * SS;  // [2,4096]

    char* ws = (char*)d_ws;
    float4* pts4    = (float4*)(ws + WS_PTS4);
    ushort* feat_nc = (ushort*)(ws + WS_FEAT);
    ushort* W1t     = (ushort*)(ws + WS_W1T);
    ushort* W2t     = (ushort*)(ws + WS_W2T);
    ushort* W3t     = (ushort*)(ws + WS_W3T);
    uint*   counts  = (uint*)(ws + WS_CNT);
    float4* lpts    = (float4*)(ws + WS_LPTS);

    hipMemsetAsync(counts, 0, (size_t)BB * GC * 4, stream);
    prep_kernel<<<NBLK, 256, 0, stream>>>(
        xyz, feat, W1, W2, W3, pts4, feat_nc, W1t, W2t, W3t, out_xyz, out_sidx,
        counts, lpts);
    fused_kernel<<<BB * SS / 4, 256, 0, stream>>>(pts4, feat_nc, counts, lpts,
                                                  W1t, W2t, W3t, b1, b2, b3,
                                                  out_feat);
}

// Round 12
// 138.766 us; speedup vs baseline: 1.0374x; 1.0126x over previous
//
#include <hip/hip_runtime.h>

#define BB 2
#define NN 16384
#define CC 64
#define SS 4096
#define KK 32
#define R2 0.16f   // RADIUS^2

// spatial grid: cell = RADIUS, 24^3 cells covering [-4.8, 4.8] (clamped; the
// clamp is monotone so the 3x3x3 neighborhood remains a superset of the ball
// for ANY input magnitude — tail points just pile into edge cells)
#define GD   24
#define GC   (GD * GD * GD)       // 13824 cells per batch
#define CAPC 112                  // per-cell bucket capacity (center cell ~66)
#define CAP  512                  // per-wave hit-list capacity (max expected ~360)
#define CAPL (CAP / 64)           // 8 register chunks for selection
#define ADDRN 1152                // per-wave candidate-address capacity (E_max~930)

typedef __bf16 bf16x8 __attribute__((ext_vector_type(8)));
typedef float  f32x4  __attribute__((ext_vector_type(4)));

#define MFMA(a, b, c) __builtin_amdgcn_mfma_f32_16x16x32_bf16((a), (b), (c), 0, 0, 0)

static __device__ __forceinline__ ushort f2bf(float f) {
    __bf16 h = (__bf16)f;
    return *(ushort*)&h;
}

static __device__ __forceinline__ int cellc(float x) {
    int i = (int)floorf(x * 2.5f + 12.0f);
    return i < 0 ? 0 : (i > GD - 1 ? GD - 1 : i);
}

// workspace section offsets (bytes), all 16B aligned
#define WS_PTS4   0          // pts4:    2*16384*16    =   524,288
#define WS_FEAT   524288     // feat_nc: 2*16384*64*2  = 4,194,304
#define WS_W1T    4718592    // 64*96*2   = 12,288
#define WS_W2T    4730880    // 64*64*2   =  8,192
#define WS_W3T    4739072    // 128*64*2  = 16,384
#define WS_CNT    4755456    // counts: 2*13824*4 = 110,592
#define WS_LPTS   4866048    // coord+id buckets: 2*13824*112*16 = 49,545,216
                             // (end 54,411,264; id packed in .w — no list[])

// prep index ranges (block-granular: T_SIDX = 328 blocks exactly)
#define T_PTS   (BB * NN)                  // 32768
#define T_W1    (T_PTS + 64 * 96)          // 38912
#define T_W2    (T_W1 + 64 * 64)           // 43008
#define T_W3    (T_W2 + 128 * 64)          // 51200
#define T_NXYZ  (T_W3 + BB * SS * 3)       // 75776
#define T_SIDX  (T_NXYZ + BB * SS)         // 83968 = 328*256
#define FEAT_B0 (T_SIDX / 256)             // 328: first feat-transpose block
#define NBLK    (FEAT_B0 + BB * (NN / 32)) // 328 + 1024 = 1352 blocks

// ---------------------------------------------------------------------------
// prep: pts4=(x,y,z,|x|^2) + coordinate+id-carrying per-cell bucket insert;
// bf16 weight transposes; coalesced new_xyz copy; samp_idx; feat [B][C][N]
// fp32 -> [B][N][C] bf16 via LDS-tiled transpose (blocks >= FEAT_B0). One
// wide launch. (Exact R8/R10 structure.)
// ---------------------------------------------------------------------------
__global__ __launch_bounds__(256) void prep_kernel(
        const float* __restrict__ xyz, const float* __restrict__ feat,
        const float* __restrict__ W1, const float* __restrict__ W2,
        const float* __restrict__ W3,
        float4* __restrict__ pts4, ushort* __restrict__ feat_nc,
        ushort* __restrict__ W1t, ushort* __restrict__ W2t,
        ushort* __restrict__ W3t,
        float* __restrict__ out_xyz, float* __restrict__ out_sidx,
        uint* __restrict__ counts, float4* __restrict__ lpts) {
    if (blockIdx.x >= FEAT_B0) {
        // ---- LDS-tiled feat transpose: one 64ch x 32pt tile per block ----
        __shared__ float tile[64][33];                 // +1 pad
        const int g = blockIdx.x - FEAT_B0;            // 0..1023
        const int b = g >> 9, n0 = (g & 511) << 5;
        const int t = threadIdx.x;
        const float* fb = feat + (size_t)b * CC * NN + n0;
        #pragma unroll
        for (int cc = 0; cc < 8; ++cc) {
            const int c = cc * 8 + (t >> 5);
            tile[c][t & 31] = fb[(size_t)c * NN + (t & 31)];
        }
        __syncthreads();
        const int p = t >> 3, c8 = t & 7;
        uint u[4];
        #pragma unroll
        for (int q = 0; q < 4; ++q) {
            u[q] = (uint)f2bf(tile[c8 * 8 + 2 * q][p]) |
                   ((uint)f2bf(tile[c8 * 8 + 2 * q + 1][p]) << 16);
        }
        *(uint4*)(feat_nc + ((size_t)b * NN + n0 + p) * 64 + c8 * 8) =
            make_uint4(u[0], u[1], u[2], u[3]);
        return;
    }
    const int t = blockIdx.x * 256 + threadIdx.x;
    if (t < T_PTS) {
        const float* p = xyz + (size_t)t * 3;
        const float x = p[0], y = p[1], z = p[2];
        pts4[t] = make_float4(x, y, z, x * x + y * y + z * z);
        const int cell = (cellc(z) * GD + cellc(y)) * GD + cellc(x);
        const int b = t >> 14, n = t & (NN - 1);
        const uint rank = atomicAdd(&counts[(size_t)b * GC + cell], 1u);
        if (rank < CAPC) {
            const size_t slot = ((size_t)b * GC + cell) * CAPC + rank;
            lpts[slot] = make_float4(x, y, z, __int_as_float(n));
        }
    } else if (t < T_W1) {
        const int i = t - T_PTS;
        const int n = i / 96, k = i - n * 96;
        float v = 0.0f;
        if (k < 64) v = W1[(3 + k) * 64 + n];
        else if (k < 67) v = W1[(k - 64) * 64 + n];
        W1t[n * 96 + k] = f2bf(v);
    } else if (t < T_W2) {
        const int i = t - T_W1;
        const int n = i >> 6, k = i & 63;
        W2t[n * 64 + k] = f2bf(W2[k * 64 + n]);
    } else if (t < T_W3) {
        const int i = t - T_W2;
        const int n = i >> 6, k = i & 63;
        W3t[n * 64 + k] = f2bf(W3[k * 128 + n]);
    } else if (t < T_NXYZ) {
        const int i = t - T_W3;              // new_xyz = xyz[:, :SS] copy
        const int b = i / (SS * 3), j = i - b * (SS * 3);
        out_xyz[i] = xyz[(size_t)b * NN * 3 + j];
    } else if (t < T_SIDX) {
        const int i = t - T_NXYZ;
        out_sidx[i] = (float)(i & (SS - 1));
    }
}

// ---------------------------------------------------------------------------
// fused: one wave = one centroid, 4-wave blocks (R8/R10 structure). Ball
// query: per-axis-factorized exact cell pruning, then the candidate ADDRESS
// LIST is materialized ONCE into LDS (per surviving cell, conflict-free
// stride-1 writes) — the candidate loop reads addresses with one ds_read_b32
// instead of re-deriving the 27-way segment select per candidate per
// iteration (the measured dominant VALU block: ~216 cy/iter x2 for the
// prefetch). Candidate SET and ORDER are bit-identical to R10. Selection
// (ballot-popcount 32-smallest), gather, MLP, maxpool-in-tails: verbatim R10.
// LDS layout per wave (6656B): addrL[1152] ints | hit[512] ints.
// ---------------------------------------------------------------------------
__global__ __launch_bounds__(256, 2) void fused_kernel(
        const float4* __restrict__ pts4, const ushort* __restrict__ feat_nc,
        const uint* __restrict__ counts, const float4* __restrict__ lpts,
        const ushort* __restrict__ W1t, const ushort* __restrict__ W2t,
        const ushort* __restrict__ W3t,
        const float* __restrict__ b1, const float* __restrict__ b2,
        const float* __restrict__ b3, float* __restrict__ out_feat) {
    const int w = threadIdx.x >> 6, lane = threadIdx.x & 63;
    const int quad = lane >> 4, mrow = lane & 15;
    const int m = lane & 31, half = lane >> 5;

    __shared__ __align__(16) ushort ldsA[4][32 * 104];   // addr|hits -> g -> h1 -> h2 (+tails)
    ushort* gbuf = ldsA[w];
    int* addrL = (int*)gbuf;                             // [0, 4608) bytes
    int* hit = (int*)(gbuf + 2304);                      // [4608, 6656) bytes

    const int xcd = blockIdx.x & 7;
    const int slot = blockIdx.x >> 3;              // 0..255
    const int b = xcd >> 2;
    const int s0 = ((xcd & 3) * 256 + slot) * 4;   // block's 4-s tile
    const int s = s0 + w;

    const float4* pb = pts4 + (size_t)b * NN;
    const ushort* fbase = feat_nc + (size_t)b * NN * 64;
    const unsigned long long ltmask = (1ull << lane) - 1ull;

    // ================= ball query via pruned cell buckets =================
    {
        const float4 c = pb[s];
        const int cx = cellc(c.x), cy = cellc(c.y), cz = cellc(c.z);
        const uint* cntb = counts + (size_t)b * GC;
        const float4* lptsb = lpts + (size_t)b * GC * CAPC;

        // per-axis squared distances to the 3 candidate cells (offsets -1,0,+1)
        // and validity; constant-indexed arrays (rule-#20 safe).
        float d2x[3], d2y[3], d2z[3];
        bool vx[3], vy[3], vz[3];
        #pragma unroll
        for (int o = 0; o < 3; ++o) {
            {
                const int X = cx + o - 1;
                vx[o] = ((unsigned)X < GD);
                const float lo = (X <= 0)      ? -1e30f : (X - 12) * 0.4f;
                const float hi = (X >= GD - 1) ?  1e30f : (X - 11) * 0.4f;
                const float d = fmaxf(fmaxf(lo - c.x, c.x - hi), 0.0f);
                d2x[o] = d * d;
            }
            {
                const int Y = cy + o - 1;
                vy[o] = ((unsigned)Y < GD);
                const float lo = (Y <= 0)      ? -1e30f : (Y - 12) * 0.4f;
                const float hi = (Y >= GD - 1) ?  1e30f : (Y - 11) * 0.4f;
                const float d = fmaxf(fmaxf(lo - c.y, c.y - hi), 0.0f);
                d2y[o] = d * d;
            }
            {
                const int Z = cz + o - 1;
                vz[o] = ((unsigned)Z < GD);
                const float lo = (Z <= 0)      ? -1e30f : (Z - 12) * 0.4f;
                const float hi = (Z >= GD - 1) ?  1e30f : (Z - 11) * 0.4f;
                const float d = fmaxf(fmaxf(lo - c.z, c.z - hi), 0.0f);
                d2z[o] = d * d;
            }
        }

        // preload the 27 cell counts (parallel issue; wave-uniform addresses)
        int cnE[27];
        #pragma unroll
        for (int e = 0; e < 27; ++e) {
            const int ez = e / 9, ey = (e / 3) % 3, ex = e % 3;
            const int ci = ((cz + ez - 1) * GD + (cy + ey - 1)) * GD + (cx + ex - 1);
            const bool ok = vx[ex] && vy[ey] && vz[ez];
            const bool reach = (d2x[ex] + d2y[ey] + d2z[ez]) < (R2 + 1e-3f);
            int cn = (ok && reach) ? (int)cntb[ok ? ci : 0] : 0;
            cnE[e] = cn < CAPC ? cn : CAPC;
        }

        // materialize the candidate address list into LDS (one-time cost;
        // replaces the per-candidate 27-way select in the hot loop)
        int tot = 0;
        #pragma unroll
        for (int e = 0; e < 27; ++e) {
            int cn = cnE[e];
            if (cn > ADDRN - tot) cn = ADDRN - tot;   // memory-safety clamp
            if (cn > 0) {                              // wave-uniform branch
                const int ez = e / 9, ey = (e / 3) % 3, ex = e % 3;
                const int base =
                    (((cz + ez - 1) * GD + (cy + ey - 1)) * GD + (cx + ex - 1)) * CAPC;
                if (lane < cn) addrL[tot + lane] = base + lane;
                if (cn > 64 && lane + 64 < cn) addrL[tot + 64 + lane] = base + 64 + lane;
                tot += cn;
            }
        }

        int cnt = 0;
        if (tot > 0) {
            float4 pc;
            {
                const int a0 = (lane < tot) ? addrL[lane] : addrL[0];
                pc = lptsb[a0];
            }
            for (int g0 = 0; g0 < tot; g0 += 64) {
                float4 pn;                           // prefetch next 64 entries
                {
                    const int gn = g0 + 64 + lane;
                    const int an = (gn < tot) ? addrL[gn] : addrL[0];
                    pn = lptsb[an];
                }
                const bool act = (g0 + lane) < tot;
                const float pw = pc.x * pc.x + pc.y * pc.y + pc.z * pc.z;
                const float d = c.w + pw - 2.0f * (c.x * pc.x + c.y * pc.y + c.z * pc.z);
                const bool h = act && (d < R2);
                const unsigned long long mk = __ballot(h);
                if (h) {
                    const int pp = cnt + __popcll(mk & ltmask);
                    if (pp < CAP) hit[pp] = __float_as_int(pc.w);
                }
                cnt += (int)__popcll(mk);
                pc = pn;
            }
        }

        // ---- keep the 32 smallest original indices (set-equivalent to the
        // reference "first nsample in index order"; maxpool ignores order) ----
        if (cnt > KK) {
            const int stored = cnt < CAP ? cnt : CAP;
            int v[CAPL];
            #pragma unroll
            for (int j = 0; j < CAPL; ++j) {
                if (j * 64 < stored) {             // chunk-gated preload
                    const int q = j * 64 + lane;
                    v[j] = (q < stored) ? hit[q] : 0x7fffffff;
                } else {
                    v[j] = 0x7fffffff;
                }
            }
            int lo = 0, hi = NN - 1;
            while (lo < hi) {                      // wave-uniform, <=14 iters
                const int mid = (lo + hi) >> 1;
                int cle = 0;
                #pragma unroll
                for (int j = 0; j < CAPL; ++j)
                    if (j * 64 < stored)           // wave-uniform chunk gate
                        cle += (int)__popcll(__ballot(v[j] <= mid));
                if (cle >= KK) hi = mid; else lo = mid + 1;
            }
            int pos = 0;                           // exactly KK selected (ids unique)
            #pragma unroll
            for (int j = 0; j < CAPL; ++j) {
                if (j * 64 < stored) {
                    const bool sel = v[j] <= lo;
                    const unsigned long long mk = __ballot(sel);
                    if (sel) hit[pos + __popcll(mk & ltmask)] = v[j];
                    pos += (int)__popcll(mk);
                }
            }
        } else if (lane < KK) {
            const int vv = (cnt == 0) ? 0 : ((lane < cnt) ? hit[lane] : hit[0]);
            hit[lane] = vv;
        }
    }

    // ================= gather: sid (LDS) -> rows -> LDS =================
    {
        const int sid = hit[m];                  // wave-private, program order
        const ushort* src = fbase + (size_t)sid * 64 + half * 32;
        ushort* dst = gbuf + m * 104 + half * 32;
        uint4 rows[4];
        #pragma unroll
        for (int i = 0; i < 4; ++i) rows[i] = *(const uint4*)(src + i * 8);
        const float4 p = pb[sid];
        const float4 cc = pb[s];
        #pragma unroll
        for (int i = 0; i < 4; ++i) *(uint4*)(dst + i * 8) = rows[i];
        if (half == 0) {
            bf16x8 rel = {(__bf16)(p.x - cc.x), (__bf16)(p.y - cc.y),
                          (__bf16)(p.z - cc.z), (__bf16)0.f,
                          (__bf16)0.f, (__bf16)0.f, (__bf16)0.f, (__bf16)0.f};
            *(bf16x8*)(gbuf + m * 104 + 64) = rel;
            *(uint4*)(gbuf + m * 104 + 88) = make_uint4(0, 0, 0, 0);
        } else {
            *(uint4*)(gbuf + m * 104 + 72) = make_uint4(0, 0, 0, 0);
            *(uint4*)(gbuf + m * 104 + 80) = make_uint4(0, 0, 0, 0);
        }
    }

    // ================= layer 1: [32x96]x[96x64] =================
    {
        f32x4 acc[2][4];
        #pragma unroll
        for (int nt = 0; nt < 4; ++nt) {
            const float bv = b1[nt * 16 + mrow];
            acc[0][nt] = (f32x4){bv, bv, bv, bv};
            acc[1][nt] = acc[0][nt];
        }
        #pragma unroll
        for (int ks = 0; ks < 3; ++ks) {
            const bf16x8 a0 = *(const bf16x8*)(gbuf + mrow * 104 + ks * 32 + quad * 8);
            const bf16x8 a1 = *(const bf16x8*)(gbuf + (16 + mrow) * 104 + ks * 32 + quad * 8);
            #pragma unroll
            for (int nt = 0; nt < 4; ++nt) {
                const bf16x8 wf = *(const bf16x8*)(W1t + (nt * 16 + mrow) * 96 + ks * 32 + quad * 8);
                acc[0][nt] = MFMA(a0, wf, acc[0][nt]);
                acc[1][nt] = MFMA(a1, wf, acc[1][nt]);
            }
        }
        #pragma unroll
        for (int mt = 0; mt < 2; ++mt)
            #pragma unroll
            for (int nt = 0; nt < 4; ++nt)
                #pragma unroll
                for (int r = 0; r < 4; ++r)
                    gbuf[(mt * 16 + quad * 4 + r) * 104 + nt * 16 + mrow] =
                        f2bf(fmaxf(acc[mt][nt][r], 0.0f));
    }

    // ================= layer 2: [32x64]x[64x64] =================
    {
        f32x4 acc[2][4];
        #pragma unroll
        for (int nt = 0; nt < 4; ++nt) {
            const float bv = b2[nt * 16 + mrow];
            acc[0][nt] = (f32x4){bv, bv, bv, bv};
            acc[1][nt] = acc[0][nt];
        }
        #pragma unroll
        for (int ks = 0; ks < 2; ++ks) {
            const bf16x8 a0 = *(const bf16x8*)(gbuf + mrow * 104 + ks * 32 + quad * 8);
            const bf16x8 a1 = *(const bf16x8*)(gbuf + (16 + mrow) * 104 + ks * 32 + quad * 8);
            #pragma unroll
            for (int nt = 0; nt < 4; ++nt) {
                const bf16x8 wf = *(const bf16x8*)(W2t + (nt * 16 + mrow) * 64 + ks * 32 + quad * 8);
                acc[0][nt] = MFMA(a0, wf, acc[0][nt]);
                acc[1][nt] = MFMA(a1, wf, acc[1][nt]);
            }
        }
        #pragma unroll
        for (int mt = 0; mt < 2; ++mt)
            #pragma unroll
            for (int nt = 0; nt < 4; ++nt)
                #pragma unroll
                for (int r = 0; r < 4; ++r)
                    gbuf[(mt * 16 + quad * 4 + r) * 104 + nt * 16 + mrow] =
                        f2bf(fmaxf(acc[mt][nt][r], 0.0f));
    }

    // ============ layer 3: [32x64]x[64x128] two n-halves + maxpool ==========
    // maxpool results go to the free 16B tail of each gbuf row (bytes 192-207;
    // MFMA reads touch only cols 0-63).
    #pragma unroll
    for (int nh = 0; nh < 2; ++nh) {
        f32x4 acc[2][4];
        #pragma unroll
        for (int ntl = 0; ntl < 4; ++ntl) {
            const float bv = b3[(nh * 4 + ntl) * 16 + mrow];
            acc[0][ntl] = (f32x4){bv, bv, bv, bv};
            acc[1][ntl] = acc[0][ntl];
        }
        #pragma unroll
        for (int ks = 0; ks < 2; ++ks) {
            const bf16x8 a0 = *(const bf16x8*)(gbuf + mrow * 104 + ks * 32 + quad * 8);
            const bf16x8 a1 = *(const bf16x8*)(gbuf + (16 + mrow) * 104 + ks * 32 + quad * 8);
            #pragma unroll
            for (int ntl = 0; ntl < 4; ++ntl) {
                const bf16x8 wf = *(const bf16x8*)(
                    W3t + ((nh * 4 + ntl) * 16 + mrow) * 64 + ks * 32 + quad * 8);
                acc[0][ntl] = MFMA(a0, wf, acc[0][ntl]);
                acc[1][ntl] = MFMA(a1, wf, acc[1][ntl]);
            }
        }
        #pragma unroll
        for (int ntl = 0; ntl < 4; ++ntl) {
            const f32x4 v0 = acc[0][ntl], v1 = acc[1][ntl];
            float mx = fmaxf(fmaxf(v0[0], v0[1]), fmaxf(v0[2], v0[3]));
            mx = fmaxf(mx, fmaxf(fmaxf(v1[0], v1[1]), fmaxf(v1[2], v1[3])));
            mx = fmaxf(mx, __shfl_xor(mx, 16));
            mx = fmaxf(mx, __shfl_xor(mx, 32));
            mx = fmaxf(mx, 0.0f);
            if (quad == 0) {
                const int ch = (nh * 4 + ntl) * 16 + mrow;
                *(float*)((char*)gbuf + (ch >> 2) * 208 + 192 + (ch & 3) * 4) = mx;
            }
        }
    }
    __syncthreads();

    // ---- epilogue: 128 ch x 4 s, float2 per thread (reads gbuf tails) ----
    {
        const int ch = threadIdx.x & 127;
        const int hf = threadIdx.x >> 7;           // 0/1
        const int tb = (ch >> 2) * 208 + 192 + (ch & 3) * 4;
        const float v0 = *(const float*)((const char*)ldsA[hf * 2] + tb);
        const float v1 = *(const float*)((const char*)ldsA[hf * 2 + 1] + tb);
        float* dst = out_feat + ((size_t)b * 128 + ch) * SS + s0 + hf * 2;
        *(float2*)dst = make_float2(v0, v1);
    }
}

// ---------------------------------------------------------------------------
extern "C" void kernel_launch(void* const* d_in, const int* in_sizes, int n_in,
                              void* d_out, int out_size, void* d_ws, size_t ws_size,
                              hipStream_t stream) {
    const float* xyz  = (const float*)d_in[0];
    const float* feat = (const float*)d_in[1];
    const float* W1   = (const float*)d_in[2];
    const float* b1   = (const float*)d_in[3];
    const float* W2   = (const float*)d_in[4];
    const float* b2   = (const float*)d_in[5];
    const float* W3   = (const float*)d_in[6];
    const float* b3   = (const float*)d_in[7];

    float* out      = (float*)d_out;
    float* out_xyz  = out;                               // [2,4096,3]
    float* out_feat = out + (size_t)BB * SS * 3;         // [2,128,4096]
    float* out_sidx = out_feat + (size_t)BB * 128 * SS;  // [2,4096]

    char* ws = (char*)d_ws;
    float4* pts4    = (float4*)(ws + WS_PTS4);
    ushort* feat_nc = (ushort*)(ws + WS_FEAT);
    ushort* W1t     = (ushort*)(ws + WS_W1T);
    ushort* W2t     = (ushort*)(ws + WS_W2T);
    ushort* W3t     = (ushort*)(ws + WS_W3T);
    uint*   counts  = (uint*)(ws + WS_CNT);
    float4* lpts    = (float4*)(ws + WS_LPTS);

    hipMemsetAsync(counts, 0, (size_t)BB * GC * 4, stream);
    prep_kernel<<<NBLK, 256, 0, stream>>>(
        xyz, feat, W1, W2, W3, pts4, feat_nc, W1t, W2t, W3t, out_xyz, out_sidx,
        counts, lpts);
    fused_kernel<<<BB * SS / 4, 256, 0, stream>>>(pts4, feat_nc, counts, lpts,
                                                  W1t, W2t, W3t, b1, b2, b3,
                                                  out_feat);
}

// Round 13
// 138.666 us; speedup vs baseline: 1.0382x; 1.0007x over previous
//
#include <hip/hip_runtime.h>

#define BB 2
#define NN 16384
#define CC 64
#define SS 4096
#define KK 32
#define R2 0.16f   // RADIUS^2

// spatial grid: cell = RADIUS, 24^3 cells covering [-4.8, 4.8] (clamped; the
// clamp is monotone so the 3x3x3 neighborhood remains a superset of the ball
// for ANY input magnitude — tail points just pile into edge cells)
#define GD   24
#define GC   (GD * GD * GD)       // 13824 cells per batch
#define CAPC 112                  // per-cell bucket capacity (center cell ~66)
#define CAP  512                  // per-wave hit-list capacity (max expected ~360)
#define CAPL (CAP / 64)           // 8 register chunks for selection
#define ADDRN 1152                // per-wave candidate-address capacity

typedef __bf16 bf16x8 __attribute__((ext_vector_type(8)));
typedef float  f32x4  __attribute__((ext_vector_type(4)));

#define MFMA(a, b, c) __builtin_amdgcn_mfma_f32_16x16x32_bf16((a), (b), (c), 0, 0, 0)

static __device__ __forceinline__ ushort f2bf(float f) {
    __bf16 h = (__bf16)f;
    return *(ushort*)&h;
}

static __device__ __forceinline__ int cellc(float x) {
    int i = (int)floorf(x * 2.5f + 12.0f);
    return i < 0 ? 0 : (i > GD - 1 ? GD - 1 : i);
}

// workspace section offsets (bytes), all 16B aligned
#define WS_PTS4   0          // pts4:    2*16384*16    =   524,288
#define WS_FEAT   524288     // feat_nc: 2*16384*64*2  = 4,194,304
#define WS_W1T    4718592    // 64*96*2   = 12,288
#define WS_W2T    4730880    // 64*64*2   =  8,192
#define WS_W3T    4739072    // 128*64*2  = 16,384
#define WS_CNT    4755456    // counts: 2*13824*4 = 110,592
#define WS_LPTS   4866048    // coord+id buckets: 2*13824*112*16 = 49,545,216
                             // (end 54,411,264; id packed in .w — no list[])

// prep index ranges (block-granular: T_SIDX = 328 blocks exactly)
#define T_PTS   (BB * NN)                  // 32768
#define T_W1    (T_PTS + 64 * 96)          // 38912
#define T_W2    (T_W1 + 64 * 64)           // 43008
#define T_W3    (T_W2 + 128 * 64)          // 51200
#define T_NXYZ  (T_W3 + BB * SS * 3)       // 75776
#define T_SIDX  (T_NXYZ + BB * SS)         // 83968 = 328*256
#define FEAT_B0 (T_SIDX / 256)             // 328: first feat-transpose block
#define NBLK    (FEAT_B0 + BB * (NN / 32)) // 328 + 1024 = 1352 blocks

// ---------------------------------------------------------------------------
// prep: pts4=(x,y,z,|x|^2) + coordinate+id-carrying per-cell bucket insert;
// bf16 weight transposes; coalesced new_xyz copy; samp_idx; feat [B][C][N]
// fp32 -> [B][N][C] bf16 via LDS-tiled transpose (blocks >= FEAT_B0). One
// wide launch. (Exact R8/R12 structure.)
// ---------------------------------------------------------------------------
__global__ __launch_bounds__(256) void prep_kernel(
        const float* __restrict__ xyz, const float* __restrict__ feat,
        const float* __restrict__ W1, const float* __restrict__ W2,
        const float* __restrict__ W3,
        float4* __restrict__ pts4, ushort* __restrict__ feat_nc,
        ushort* __restrict__ W1t, ushort* __restrict__ W2t,
        ushort* __restrict__ W3t,
        float* __restrict__ out_xyz, float* __restrict__ out_sidx,
        uint* __restrict__ counts, float4* __restrict__ lpts) {
    if (blockIdx.x >= FEAT_B0) {
        // ---- LDS-tiled feat transpose: one 64ch x 32pt tile per block ----
        __shared__ float tile[64][33];                 // +1 pad
        const int g = blockIdx.x - FEAT_B0;            // 0..1023
        const int b = g >> 9, n0 = (g & 511) << 5;
        const int t = threadIdx.x;
        const float* fb = feat + (size_t)b * CC * NN + n0;
        #pragma unroll
        for (int cc = 0; cc < 8; ++cc) {
            const int c = cc * 8 + (t >> 5);
            tile[c][t & 31] = fb[(size_t)c * NN + (t & 31)];
        }
        __syncthreads();
        const int p = t >> 3, c8 = t & 7;
        uint u[4];
        #pragma unroll
        for (int q = 0; q < 4; ++q) {
            u[q] = (uint)f2bf(tile[c8 * 8 + 2 * q][p]) |
                   ((uint)f2bf(tile[c8 * 8 + 2 * q + 1][p]) << 16);
        }
        *(uint4*)(feat_nc + ((size_t)b * NN + n0 + p) * 64 + c8 * 8) =
            make_uint4(u[0], u[1], u[2], u[3]);
        return;
    }
    const int t = blockIdx.x * 256 + threadIdx.x;
    if (t < T_PTS) {
        const float* p = xyz + (size_t)t * 3;
        const float x = p[0], y = p[1], z = p[2];
        pts4[t] = make_float4(x, y, z, x * x + y * y + z * z);
        const int cell = (cellc(z) * GD + cellc(y)) * GD + cellc(x);
        const int b = t >> 14, n = t & (NN - 1);
        const uint rank = atomicAdd(&counts[(size_t)b * GC + cell], 1u);
        if (rank < CAPC) {
            const size_t slot = ((size_t)b * GC + cell) * CAPC + rank;
            lpts[slot] = make_float4(x, y, z, __int_as_float(n));
        }
    } else if (t < T_W1) {
        const int i = t - T_PTS;
        const int n = i / 96, k = i - n * 96;
        float v = 0.0f;
        if (k < 64) v = W1[(3 + k) * 64 + n];
        else if (k < 67) v = W1[(k - 64) * 64 + n];
        W1t[n * 96 + k] = f2bf(v);
    } else if (t < T_W2) {
        const int i = t - T_W1;
        const int n = i >> 6, k = i & 63;
        W2t[n * 64 + k] = f2bf(W2[k * 64 + n]);
    } else if (t < T_W3) {
        const int i = t - T_W2;
        const int n = i >> 6, k = i & 63;
        W3t[n * 64 + k] = f2bf(W3[k * 128 + n]);
    } else if (t < T_NXYZ) {
        const int i = t - T_W3;              // new_xyz = xyz[:, :SS] copy
        const int b = i / (SS * 3), j = i - b * (SS * 3);
        out_xyz[i] = xyz[(size_t)b * NN * 3 + j];
    } else if (t < T_SIDX) {
        const int i = t - T_NXYZ;
        out_sidx[i] = (float)(i & (SS - 1));
    }
}

// ---------------------------------------------------------------------------
// fused: one wave = one centroid, 4-wave blocks (R8/R12 structure). Ball
// query: per-axis-factorized exact cell pruning; candidate addresses
// materialized ONCE into LDS (R12, cut VALUBusy 37->30%); candidate loop now
// CHUNK-4 PIPELINED: 4 independent 64-lane gathers issued back-to-back, then
// processed — one L3-latency exposure per 256 candidates instead of one per
// 64 (R12 showed the kernel is memory-stall-bound: 70% of cycles no-issue).
// Candidate SET and ORDER identical to R12. Selection, gather, MLP,
// maxpool-in-tails: verbatim R12.
// LDS layout per wave (6656B): addrL[1152] ints | hit[512] ints.
// ---------------------------------------------------------------------------
__global__ __launch_bounds__(256, 2) void fused_kernel(
        const float4* __restrict__ pts4, const ushort* __restrict__ feat_nc,
        const uint* __restrict__ counts, const float4* __restrict__ lpts,
        const ushort* __restrict__ W1t, const ushort* __restrict__ W2t,
        const ushort* __restrict__ W3t,
        const float* __restrict__ b1, const float* __restrict__ b2,
        const float* __restrict__ b3, float* __restrict__ out_feat) {
    const int w = threadIdx.x >> 6, lane = threadIdx.x & 63;
    const int quad = lane >> 4, mrow = lane & 15;
    const int m = lane & 31, half = lane >> 5;

    __shared__ __align__(16) ushort ldsA[4][32 * 104];   // addr|hits -> g -> h1 -> h2 (+tails)
    ushort* gbuf = ldsA[w];
    int* addrL = (int*)gbuf;                             // [0, 4608) bytes
    int* hit = (int*)(gbuf + 2304);                      // [4608, 6656) bytes

    const int xcd = blockIdx.x & 7;
    const int slot = blockIdx.x >> 3;              // 0..255
    const int b = xcd >> 2;
    const int s0 = ((xcd & 3) * 256 + slot) * 4;   // block's 4-s tile
    const int s = s0 + w;

    const float4* pb = pts4 + (size_t)b * NN;
    const ushort* fbase = feat_nc + (size_t)b * NN * 64;
    const unsigned long long ltmask = (1ull << lane) - 1ull;

    // ================= ball query via pruned cell buckets =================
    {
        const float4 c = pb[s];
        const int cx = cellc(c.x), cy = cellc(c.y), cz = cellc(c.z);
        const uint* cntb = counts + (size_t)b * GC;
        const float4* lptsb = lpts + (size_t)b * GC * CAPC;

        // per-axis squared distances to the 3 candidate cells (offsets -1,0,+1)
        // and validity; constant-indexed arrays (rule-#20 safe).
        float d2x[3], d2y[3], d2z[3];
        bool vx[3], vy[3], vz[3];
        #pragma unroll
        for (int o = 0; o < 3; ++o) {
            {
                const int X = cx + o - 1;
                vx[o] = ((unsigned)X < GD);
                const float lo = (X <= 0)      ? -1e30f : (X - 12) * 0.4f;
                const float hi = (X >= GD - 1) ?  1e30f : (X - 11) * 0.4f;
                const float d = fmaxf(fmaxf(lo - c.x, c.x - hi), 0.0f);
                d2x[o] = d * d;
            }
            {
                const int Y = cy + o - 1;
                vy[o] = ((unsigned)Y < GD);
                const float lo = (Y <= 0)      ? -1e30f : (Y - 12) * 0.4f;
                const float hi = (Y >= GD - 1) ?  1e30f : (Y - 11) * 0.4f;
                const float d = fmaxf(fmaxf(lo - c.y, c.y - hi), 0.0f);
                d2y[o] = d * d;
            }
            {
                const int Z = cz + o - 1;
                vz[o] = ((unsigned)Z < GD);
                const float lo = (Z <= 0)      ? -1e30f : (Z - 12) * 0.4f;
                const float hi = (Z >= GD - 1) ?  1e30f : (Z - 11) * 0.4f;
                const float d = fmaxf(fmaxf(lo - c.z, c.z - hi), 0.0f);
                d2z[o] = d * d;
            }
        }

        // preload the 27 cell counts (parallel issue; wave-uniform addresses)
        int cnE[27];
        #pragma unroll
        for (int e = 0; e < 27; ++e) {
            const int ez = e / 9, ey = (e / 3) % 3, ex = e % 3;
            const int ci = ((cz + ez - 1) * GD + (cy + ey - 1)) * GD + (cx + ex - 1);
            const bool ok = vx[ex] && vy[ey] && vz[ez];
            const bool reach = (d2x[ex] + d2y[ey] + d2z[ez]) < (R2 + 1e-3f);
            int cn = (ok && reach) ? (int)cntb[ok ? ci : 0] : 0;
            cnE[e] = cn < CAPC ? cn : CAPC;
        }

        // materialize the candidate address list into LDS (one-time cost;
        // replaces the per-candidate 27-way select in the hot loop)
        int tot = 0;
        #pragma unroll
        for (int e = 0; e < 27; ++e) {
            int cn = cnE[e];
            if (cn > ADDRN - tot) cn = ADDRN - tot;   // memory-safety clamp
            if (cn > 0) {                              // wave-uniform branch
                const int ez = e / 9, ey = (e / 3) % 3, ex = e % 3;
                const int base =
                    (((cz + ez - 1) * GD + (cy + ey - 1)) * GD + (cx + ex - 1)) * CAPC;
                if (lane < cn) addrL[tot + lane] = base + lane;
                if (cn > 64 && lane + 64 < cn) addrL[tot + 64 + lane] = base + 64 + lane;
                tot += cn;
            }
        }

        int cnt = 0;
        if (tot > 0) {
            // chunk-4 pipelined candidate loop: 4 independent gathers issued
            // back-to-back, then processed (one latency per 256 candidates)
            for (int g0 = 0; g0 < tot; g0 += 256) {
                float4 q[4];
                #pragma unroll
                for (int k = 0; k < 4; ++k) {
                    const int g = g0 + k * 64 + lane;
                    const int a = (g < tot) ? addrL[g] : addrL[0];
                    q[k] = lptsb[a];
                }
                #pragma unroll
                for (int k = 0; k < 4; ++k) {
                    const int g = g0 + k * 64;
                    if (g < tot) {                     // wave-uniform gate
                        const bool act = (g + lane) < tot;
                        const float4 pc = q[k];
                        const float pw = pc.x * pc.x + pc.y * pc.y + pc.z * pc.z;
                        const float d = c.w + pw -
                            2.0f * (c.x * pc.x + c.y * pc.y + c.z * pc.z);
                        const bool h = act && (d < R2);
                        const unsigned long long mk = __ballot(h);
                        if (h) {
                            const int pp = cnt + __popcll(mk & ltmask);
                            if (pp < CAP) hit[pp] = __float_as_int(pc.w);
                        }
                        cnt += (int)__popcll(mk);
                    }
                }
            }
        }

        // ---- keep the 32 smallest original indices (set-equivalent to the
        // reference "first nsample in index order"; maxpool ignores order) ----
        if (cnt > KK) {
            const int stored = cnt < CAP ? cnt : CAP;
            int v[CAPL];
            #pragma unroll
            for (int j = 0; j < CAPL; ++j) {
                if (j * 64 < stored) {             // chunk-gated preload
                    const int q = j * 64 + lane;
                    v[j] = (q < stored) ? hit[q] : 0x7fffffff;
                } else {
                    v[j] = 0x7fffffff;
                }
            }
            int lo = 0, hi = NN - 1;
            while (lo < hi) {                      // wave-uniform, <=14 iters
                const int mid = (lo + hi) >> 1;
                int cle = 0;
                #pragma unroll
                for (int j = 0; j < CAPL; ++j)
                    if (j * 64 < stored)           // wave-uniform chunk gate
                        cle += (int)__popcll(__ballot(v[j] <= mid));
                if (cle >= KK) hi = mid; else lo = mid + 1;
            }
            int pos = 0;                           // exactly KK selected (ids unique)
            #pragma unroll
            for (int j = 0; j < CAPL; ++j) {
                if (j * 64 < stored) {
                    const bool sel = v[j] <= lo;
                    const unsigned long long mk = __ballot(sel);
                    if (sel) hit[pos + __popcll(mk & ltmask)] = v[j];
                    pos += (int)__popcll(mk);
                }
            }
        } else if (lane < KK) {
            const int vv = (cnt == 0) ? 0 : ((lane < cnt) ? hit[lane] : hit[0]);
            hit[lane] = vv;
        }
    }

    // ================= gather: sid (LDS) -> rows -> LDS =================
    {
        const int sid = hit[m];                  // wave-private, program order
        const ushort* src = fbase + (size_t)sid * 64 + half * 32;
        ushort* dst = gbuf + m * 104 + half * 32;
        uint4 rows[4];
        #pragma unroll
        for (int i = 0; i < 4; ++i) rows[i] = *(const uint4*)(src + i * 8);
        const float4 p = pb[sid];
        const float4 cc = pb[s];
        #pragma unroll
        for (int i = 0; i < 4; ++i) *(uint4*)(dst + i * 8) = rows[i];
        if (half == 0) {
            bf16x8 rel = {(__bf16)(p.x - cc.x), (__bf16)(p.y - cc.y),
                          (__bf16)(p.z - cc.z), (__bf16)0.f,
                          (__bf16)0.f, (__bf16)0.f, (__bf16)0.f, (__bf16)0.f};
            *(bf16x8*)(gbuf + m * 104 + 64) = rel;
            *(uint4*)(gbuf + m * 104 + 88) = make_uint4(0, 0, 0, 0);
        } else {
            *(uint4*)(gbuf + m * 104 + 72) = make_uint4(0, 0, 0, 0);
            *(uint4*)(gbuf + m * 104 + 80) = make_uint4(0, 0, 0, 0);
        }
    }

    // ================= layer 1: [32x96]x[96x64] =================
    {
        f32x4 acc[2][4];
        #pragma unroll
        for (int nt = 0; nt < 4; ++nt) {
            const float bv = b1[nt * 16 + mrow];
            acc[0][nt] = (f32x4){bv, bv, bv, bv};
            acc[1][nt] = acc[0][nt];
        }
        #pragma unroll
        for (int ks = 0; ks < 3; ++ks) {
            const bf16x8 a0 = *(const bf16x8*)(gbuf + mrow * 104 + ks * 32 + quad * 8);
            const bf16x8 a1 = *(const bf16x8*)(gbuf + (16 + mrow) * 104 + ks * 32 + quad * 8);
            #pragma unroll
            for (int nt = 0; nt < 4; ++nt) {
                const bf16x8 wf = *(const bf16x8*)(W1t + (nt * 16 + mrow) * 96 + ks * 32 + quad * 8);
                acc[0][nt] = MFMA(a0, wf, acc[0][nt]);
                acc[1][nt] = MFMA(a1, wf, acc[1][nt]);
            }
        }
        #pragma unroll
        for (int mt = 0; mt < 2; ++mt)
            #pragma unroll
            for (int nt = 0; nt < 4; ++nt)
                #pragma unroll
                for (int r = 0; r < 4; ++r)
                    gbuf[(mt * 16 + quad * 4 + r) * 104 + nt * 16 + mrow] =
                        f2bf(fmaxf(acc[mt][nt][r], 0.0f));
    }

    // ================= layer 2: [32x64]x[64x64] =================
    {
        f32x4 acc[2][4];
        #pragma unroll
        for (int nt = 0; nt < 4; ++nt) {
            const float bv = b2[nt * 16 + mrow];
            acc[0][nt] = (f32x4){bv, bv, bv, bv};
            acc[1][nt] = acc[0][nt];
        }
        #pragma unroll
        for (int ks = 0; ks < 2; ++ks) {
            const bf16x8 a0 = *(const bf16x8*)(gbuf + mrow * 104 + ks * 32 + quad * 8);
            const bf16x8 a1 = *(const bf16x8*)(gbuf + (16 + mrow) * 104 + ks * 32 + quad * 8);
            #pragma unroll
            for (int nt = 0; nt < 4; ++nt) {
                const bf16x8 wf = *(const bf16x8*)(W2t + (nt * 16 + mrow) * 64 + ks * 32 + quad * 8);
                acc[0][nt] = MFMA(a0, wf, acc[0][nt]);
                acc[1][nt] = MFMA(a1, wf, acc[1][nt]);
            }
        }
        #pragma unroll
        for (int mt = 0; mt < 2; ++mt)
            #pragma unroll
            for (int nt = 0; nt < 4; ++nt)
                #pragma unroll
                for (int r = 0; r < 4; ++r)
                    gbuf[(mt * 16 + quad * 4 + r) * 104 + nt * 16 + mrow] =
                        f2bf(fmaxf(acc[mt][nt][r], 0.0f));
    }

    // ============ layer 3: [32x64]x[64x128] two n-halves + maxpool ==========
    // maxpool results go to the free 16B tail of each gbuf row (bytes 192-207;
    // MFMA reads touch only cols 0-63).
    #pragma unroll
    for (int nh = 0; nh < 2; ++nh) {
        f32x4 acc[2][4];
        #pragma unroll
        for (int ntl = 0; ntl < 4; ++ntl) {
            const float bv = b3[(nh * 4 + ntl) * 16 + mrow];
            acc[0][ntl] = (f32x4){bv, bv, bv, bv};
            acc[1][ntl] = acc[0][ntl];
        }
        #pragma unroll
        for (int ks = 0; ks < 2; ++ks) {
            const bf16x8 a0 = *(const bf16x8*)(gbuf + mrow * 104 + ks * 32 + quad * 8);
            const bf16x8 a1 = *(const bf16x8*)(gbuf + (16 + mrow) * 104 + ks * 32 + quad * 8);
            #pragma unroll
            for (int ntl = 0; ntl < 4; ++ntl) {
                const bf16x8 wf = *(const bf16x8*)(
                    W3t + ((nh * 4 + ntl) * 16 + mrow) * 64 + ks * 32 + quad * 8);
                acc[0][ntl] = MFMA(a0, wf, acc[0][ntl]);
                acc[1][ntl] = MFMA(a1, wf, acc[1][ntl]);
            }
        }
        #pragma unroll
        for (int ntl = 0; ntl < 4; ++ntl) {
            const f32x4 v0 = acc[0][ntl], v1 = acc[1][ntl];
            float mx = fmaxf(fmaxf(v0[0], v0[1]), fmaxf(v0[2], v0[3]));
            mx = fmaxf(mx, fmaxf(fmaxf(v1[0], v1[1]), fmaxf(v1[2], v1[3])));
            mx = fmaxf(mx, __shfl_xor(mx, 16));
            mx = fmaxf(mx, __shfl_xor(mx, 32));
            mx = fmaxf(mx, 0.0f);
            if (quad == 0) {
                const int ch = (nh * 4 + ntl) * 16 + mrow;
                *(float*)((char*)gbuf + (ch >> 2) * 208 + 192 + (ch & 3) * 4) = mx;
            }
        }
    }
    __syncthreads();

    // ---- epilogue: 128 ch x 4 s, float2 per thread (reads gbuf tails) ----
    {
        const int ch = threadIdx.x & 127;
        const int hf = threadIdx.x >> 7;           // 0/1
        const int tb = (ch >> 2) * 208 + 192 + (ch & 3) * 4;
        const float v0 = *(const float*)((const char*)ldsA[hf * 2] + tb);
        const float v1 = *(const float*)((const char*)ldsA[hf * 2 + 1] + tb);
        float* dst = out_feat + ((size_t)b * 128 + ch) * SS + s0 + hf * 2;
        *(float2*)dst = make_float2(v0, v1);
    }
}

// ---------------------------------------------------------------------------
extern "C" void kernel_launch(void* const* d_in, const int* in_sizes, int n_in,
                              void* d_out, int out_size, void* d_ws, size_t ws_size,
                              hipStream_t stream) {
    const float* xyz  = (const float*)d_in[0];
    const float* feat = (const float*)d_in[1];
    const float* W1   = (const float*)d_in[2];
    const float* b1   = (const float*)d_in[3];
    const float* W2   = (const float*)d_in[4];
    const float* b2   = (const float*)d_in[5];
    const float* W3   = (const float*)d_in[6];
    const float* b3   = (const float*)d_in[7];

    float* out      = (float*)d_out;
    float* out_xyz  = out;                               // [2,4096,3]
    float* out_feat = out + (size_t)BB * SS * 3;         // [2,128,4096]
    float* out_sidx = out_feat + (size_t)BB * 128 * SS;  // [2,4096]

    char* ws = (char*)d_ws;
    float4* pts4    = (float4*)(ws + WS_PTS4);
    ushort* feat_nc = (ushort*)(ws + WS_FEAT);
    ushort* W1t     = (ushort*)(ws + WS_W1T);
    ushort* W2t     = (ushort*)(ws + WS_W2T);
    ushort* W3t     = (ushort*)(ws + WS_W3T);
    uint*   counts  = (uint*)(ws + WS_CNT);
    float4* lpts    = (float4*)(ws + WS_LPTS);

    hipMemsetAsync(counts, 0, (size_t)BB * GC * 4, stream);
    prep_kernel<<<NBLK, 256, 0, stream>>>(
        xyz, feat, W1, W2, W3, pts4, feat_nc, W1t, W2t, W3t, out_xyz, out_sidx,
        counts, lpts);
    fused_kernel<<<BB * SS / 4, 256, 0, stream>>>(pts4, feat_nc, counts, lpts,
                                                  W1t, W2t, W3t, b1, b2, b3,
                                                  out_feat);
}